// Round 3
// baseline (435.913 us; speedup 1.0000x reference)
//
#include <hip/hip_runtime.h>
#include <hip/hip_bf16.h>
#include <cmath>

// ---------------- problem constants ----------------
#define T_TOKENS 4096   // 2*2048
#define DMODEL   1024
#define HDIM     2048
#define NEXP     8
#define BM 256          // M-tile (rows padded per expert to 256)
#define BK 64
#define MAXROWS 10240   // 8192 routed rows + worst-case per-expert padding to 256
#define MTILES  (MAXROWS / BM)   // 40

typedef __bf16 bf16;
typedef __bf16 bf16x8 __attribute__((ext_vector_type(8)));
typedef __bf16 bf16x4 __attribute__((ext_vector_type(4)));
typedef float  f32x4  __attribute__((ext_vector_type(4)));

// async global->LDS, 16B per lane (LDS dest must be uniform base + lane*16)
__device__ inline void gload_lds16(const void* g, void* l) {
  __builtin_amdgcn_global_load_lds(
      (const __attribute__((address_space(1))) void*)g,
      (__attribute__((address_space(3))) void*)l, 16, 0, 0);
}

// ---------------- router: logits -> softmax -> top2 -> weights; also x -> bf16 ----------------
__global__ __launch_bounds__(256) void router_kernel(
    const float* __restrict__ x, const float* __restrict__ gw,
    bf16* __restrict__ xb, int* __restrict__ es, float* __restrict__ wsv,
    int* __restrict__ counts)
{
  int wid = threadIdx.x >> 6, lane = threadIdx.x & 63;
  int t = blockIdx.x * 4 + wid;
  if (t >= T_TOKENS) return;
  const float* xrow = x + (size_t)t * DMODEL;

  double acc[NEXP];
#pragma unroll
  for (int e = 0; e < NEXP; e++) acc[e] = 0.0;

#pragma unroll
  for (int i = 0; i < 4; i++) {
    int d0 = (i * 64 + lane) * 4;
    float4 xv = *(const float4*)(xrow + d0);
    bf16x4 o = { (bf16)xv.x, (bf16)xv.y, (bf16)xv.z, (bf16)xv.w };
    *(bf16x4*)(xb + (size_t)t * DMODEL + d0) = o;
    const float* g0 = gw + (size_t)d0 * NEXP;
    float xs[4] = { xv.x, xv.y, xv.z, xv.w };
#pragma unroll
    for (int j = 0; j < 4; j++)
#pragma unroll
      for (int e = 0; e < NEXP; e++)
        acc[e] += (double)xs[j] * (double)g0[j * NEXP + e];
  }
#pragma unroll
  for (int e = 0; e < NEXP; e++) {
    double v = acc[e];
#pragma unroll
    for (int m = 32; m >= 1; m >>= 1) v += __shfl_xor(v, m, 64);
    acc[e] = v;
  }
  if (lane == 0) {
    float l[NEXP], p[NEXP];
    float mx = -1e30f;
#pragma unroll
    for (int e = 0; e < NEXP; e++) { l[e] = (float)acc[e]; mx = fmaxf(mx, l[e]); }
    float s = 0.f;
#pragma unroll
    for (int e = 0; e < NEXP; e++) { p[e] = __expf(l[e] - mx); s += p[e]; }
#pragma unroll
    for (int e = 0; e < NEXP; e++) p[e] /= s;
    int i0 = 0;
#pragma unroll
    for (int e = 1; e < NEXP; e++) if (p[e] > p[i0]) i0 = e;
    int i1 = (i0 == 0) ? 1 : 0;
#pragma unroll
    for (int e = 0; e < NEXP; e++) if (e != i0 && p[e] > p[i1]) i1 = e;
    float wA = p[i0], wB = p[i1];
    float dn = wA + wB + 1e-9f;
    wA /= dn; wB /= dn;
    es[t] = i0; es[T_TOKENS + t] = i1;
    wsv[t] = wA; wsv[T_TOKENS + t] = wB;
    atomicAdd(&counts[i0], 1);
    atomicAdd(&counts[i1], 1);
  }
}

// ---------------- padded prefix offsets (pad to BM=256), zero cursors ----------------
__global__ void offsets_kernel(const int* __restrict__ counts, int* __restrict__ off,
                               int* __restrict__ cursor)
{
  if (threadIdx.x == 0) {
    int o = 0;
    for (int e = 0; e < NEXP; e++) {
      off[e] = o;
      o += ((counts[e] + BM - 1) / BM) * BM;
    }
    off[NEXP] = o;
  }
  if (threadIdx.x < NEXP) cursor[threadIdx.x] = 0;
}

// ---------------- token -> row assignment ----------------
__global__ void assign_kernel(const int* __restrict__ es, const float* __restrict__ wsv,
                              const int* __restrict__ off, int* __restrict__ cursor,
                              int* __restrict__ perm, float* __restrict__ wt)
{
  int t = blockIdx.x * blockDim.x + threadIdx.x;
  if (t >= T_TOKENS) return;
#pragma unroll
  for (int s = 0; s < 2; s++) {
    int e = es[s * T_TOKENS + t];
    int slot = atomicAdd(&cursor[e], 1);
    int r = off[e] + slot;
    perm[r] = t;
    wt[r] = wsv[s * T_TOKENS + t];
  }
}

// ---------------- weight fp32 [E][R][C] -> bf16 transposed [E][C][R] ----------------
__global__ __launch_bounds__(256) void transpose_cvt_kernel(
    const float* __restrict__ src, bf16* __restrict__ dst, int R, int C)
{
  __shared__ bf16 tile[64][66];
  int e = blockIdx.z;
  int r0 = blockIdx.y * 64, c0 = blockIdx.x * 64;
  const float* s = src + (size_t)e * R * C;
  bf16* d = dst + (size_t)e * R * C;
  int tr = threadIdx.x >> 4;          // 0..15
  int tc4 = (threadIdx.x & 15) * 4;   // 0..60
#pragma unroll
  for (int i = 0; i < 4; i++) {
    int r = tr + i * 16;
    float4 v = *(const float4*)(s + (size_t)(r0 + r) * C + c0 + tc4);
    tile[tc4 + 0][r] = (bf16)v.x;
    tile[tc4 + 1][r] = (bf16)v.y;
    tile[tc4 + 2][r] = (bf16)v.z;
    tile[tc4 + 3][r] = (bf16)v.w;
  }
  __syncthreads();
  int cc0 = threadIdx.x >> 3;         // 0..31
  int ch = (threadIdx.x & 7) * 8;     // 0..56
#pragma unroll
  for (int i = 0; i < 2; i++) {
    int cc = cc0 + i * 32;
    const unsigned int* rp = (const unsigned int*)&tile[cc][0];
    unsigned int u0 = rp[ch / 2 + 0];
    unsigned int u1 = rp[ch / 2 + 1];
    unsigned int u2 = rp[ch / 2 + 2];
    unsigned int u3 = rp[ch / 2 + 3];
    uint4 o = { u0, u1, u2, u3 };
    *(uint4*)(d + (size_t)(c0 + cc) * R + r0 + ch) = o;
  }
}

// ---------------- out = bias (broadcast) ----------------
__global__ void out_init_kernel(float* __restrict__ out, const float* __restrict__ bias)
{
  int i = blockIdx.x * blockDim.x + threadIdx.x;
  out[i] = bias[i & (DMODEL - 1)];
}

// ---------------- 256-wide deep-pipelined MFMA GEMM (T1+T2+T3+T4+T5) ----------------
// 512 threads = 8 waves (2M x 4N). Per-wave output 128 x (FN*16).
// BN = FN*64. G1: FN=4 (BN=256). G2: FN=2 (BN=128). Grid = MTILES*8, nt = bid&7
// (pins each N-slab to one XCD: 4 MB weight slab fits XCD L2).
// LDS XOR swizzle: byte ^= (row&7)<<4, applied on read; staging keeps LDS linear
// and pre-swizzles the GLOBAL source column (rule #21).
template<int KDIM, int NDIM, int FN, bool GELU_STORE>
__global__ __launch_bounds__(512, 2) void moe_gemm256_kernel(
    const bf16* __restrict__ A, const bf16* __restrict__ W,
    bf16* __restrict__ hidden, float* __restrict__ out,
    const int* __restrict__ perm, const float* __restrict__ wt,
    const int* __restrict__ off)
{
  constexpr int BN_ = FN * 64;
  constexpr int NQ  = FN / 2;       // n-frags per phase
  constexpr int NT  = KDIM / BK;

  int nt = blockIdx.x & 7;
  int mt = blockIdx.x >> 3;
  int row0 = mt * BM;
  int total = off[NEXP];
  if (row0 >= total) return;
  int e = 0;
  while (row0 >= off[e + 1]) e++;
  int n0 = nt * BN_;
  const bf16* Wb = W + (size_t)e * NDIM * KDIM;

  __shared__ bf16 As[2][256 * 64];
  __shared__ bf16 Bs[2][BN_ * 64];

  int tid  = threadIdx.x;
  int lane = tid & 63;
  int wid  = tid >> 6;
  int wm   = wid >> 2;              // 0..1
  int wn   = wid & 3;               // 0..3
  int l15  = lane & 15;
  int hi16 = (lane >> 4) << 4;      // k-group byte offset within row

  unsigned aoff[4];
#pragma unroll
  for (int i = 0; i < 4; ++i) {
    int r = i * 64 + (tid >> 3);
    unsigned g;
    if (GELU_STORE) { int p = perm[row0 + r]; g = (p < 0) ? 0u : (unsigned)p; }
    else            { g = (unsigned)(row0 + r); }
    aoff[i] = g * KDIM;
  }
  unsigned boff[FN];
#pragma unroll
  for (int i = 0; i < FN; ++i)
    boff[i] = (unsigned)(n0 + i * 64 + (tid >> 3)) * KDIM;

  int sc8 = tid & 7;

  f32x4 acc[8][FN];
#pragma unroll
  for (int am = 0; am < 8; ++am)
#pragma unroll
    for (int an = 0; an < FN; ++an)
      acc[am][an] = (f32x4){0.f, 0.f, 0.f, 0.f};

  auto STAGE = [&](int bb, int t) {
    int k0 = t * BK;
#pragma unroll
    for (int i = 0; i < 4; ++i) {
      int r = i * 64 + (tid >> 3);
      int c8 = sc8 ^ (r & 7);                       // inverse-swizzled source col
      gload_lds16(A + aoff[i] + k0 + c8 * 8,
                  &As[bb][(unsigned)(i * 512 + tid) * 8]);
    }
#pragma unroll
    for (int i = 0; i < FN; ++i) {
      int r = i * 64 + (tid >> 3);
      int c8 = sc8 ^ (r & 7);
      gload_lds16(Wb + boff[i] + k0 + c8 * 8,
                  &Bs[bb][(unsigned)(i * 512 + tid) * 8]);
    }
  };

  STAGE(0, 0);
  asm volatile("s_waitcnt vmcnt(0)" ::: "memory");
  __builtin_amdgcn_s_barrier();

  bf16x8 af[4][2];
  bf16x8 bfg[NQ][2];

  for (int t = 0; t < NT; ++t) {
    int b = t & 1;
    const char* asB = (const char*)&As[b][0];
    const char* bsB = (const char*)&Bs[b][0];
#pragma unroll
    for (int q = 0; q < 4; ++q) {
      const int qm = q >> 1, qn = q & 1;
      if (q == 0 && t + 1 < NT) STAGE(b ^ 1, t + 1);  // all prefetch issued early
      if (qn == 0) {                                   // a-frags reused across qn
#pragma unroll
        for (int m = 0; m < 4; ++m)
#pragma unroll
          for (int kk = 0; kk < 2; ++kk) {
            int r  = wm * 128 + qm * 64 + m * 16 + l15;
            int cb = (kk * 64 + hi16) ^ ((r & 7) << 4);
            af[m][kk] = *(const bf16x8*)(asB + r * 128 + cb);
          }
      }
#pragma unroll
      for (int n = 0; n < NQ; ++n)
#pragma unroll
        for (int kk = 0; kk < 2; ++kk) {
          int r  = wn * (FN * 16) + (qn * NQ + n) * 16 + l15;
          int cb = (kk * 64 + hi16) ^ ((r & 7) << 4);
          bfg[n][kk] = *(const bf16x8*)(bsB + r * 128 + cb);
        }
      __builtin_amdgcn_s_barrier();
      asm volatile("s_waitcnt lgkmcnt(0)" ::: "memory");
      __builtin_amdgcn_sched_barrier(0);               // rule #18
      __builtin_amdgcn_s_setprio(1);
#pragma unroll
      for (int m = 0; m < 4; ++m)
#pragma unroll
        for (int n = 0; n < NQ; ++n)
#pragma unroll
          for (int kk = 0; kk < 2; ++kk)
            acc[qm * 4 + m][qn * NQ + n] = __builtin_amdgcn_mfma_f32_16x16x32_bf16(
                af[m][kk], bfg[n][kk], acc[qm * 4 + m][qn * NQ + n], 0, 0, 0);
      __builtin_amdgcn_s_setprio(0);
      __builtin_amdgcn_sched_barrier(0);
      if (q == 3 && t + 1 < NT)                        // loads are >=3 phases old here
        asm volatile("s_waitcnt vmcnt(0)" ::: "memory");
      __builtin_amdgcn_s_barrier();
    }
  }

  // epilogue: C/D layout col = lane&15, row = (lane>>4)*4 + j
#pragma unroll
  for (int am = 0; am < 8; ++am) {
    int rb = row0 + wm * 128 + am * 16 + ((lane >> 4) << 2);
#pragma unroll
    for (int j = 0; j < 4; ++j) {
      int rg = rb + j;
      if (GELU_STORE) {
#pragma unroll
        for (int an = 0; an < FN; ++an) {
          float v  = acc[am][an][j];
          float gv = 0.5f * v * (1.0f + erff(v * 0.70710678118654752f));
          hidden[(unsigned)rg * NDIM + (n0 + wn * (FN * 16) + an * 16 + l15)] = (bf16)gv;
        }
      } else {
        int p = perm[rg];
        if (p >= 0) {
          float w = wt[rg];
#pragma unroll
          for (int an = 0; an < FN; ++an)
            atomicAdd(&out[(unsigned)p * DMODEL + (n0 + wn * (FN * 16) + an * 16 + l15)],
                      w * acc[am][an][j]);
        }
      }
    }
  }
}

// ---------------- host ----------------
extern "C" void kernel_launch(void* const* d_in, const int* in_sizes, int n_in,
                              void* d_out, int out_size, void* d_ws, size_t ws_size,
                              hipStream_t stream)
{
  const float* x    = (const float*)d_in[0];
  const float* gw   = (const float*)d_in[1];
  const float* w1   = (const float*)d_in[2];
  const float* w2   = (const float*)d_in[3];
  const float* bias = (const float*)d_in[4];
  float* out = (float*)d_out;

  char* ws = (char*)d_ws;
  size_t o = 0;
  auto alloc = [&](size_t bytes) {
    void* p = ws + o;
    o = (o + bytes + 255) & ~(size_t)255;
    return p;
  };
  bf16*  xb     = (bf16*) alloc((size_t)T_TOKENS * DMODEL * 2);
  bf16*  w1t    = (bf16*) alloc((size_t)NEXP * HDIM * DMODEL * 2);   // [E][H][D]
  bf16*  w2t    = (bf16*) alloc((size_t)NEXP * DMODEL * HDIM * 2);   // [E][D][H]
  bf16*  hidden = (bf16*) alloc((size_t)MAXROWS * HDIM * 2);
  int*   perm   = (int*)  alloc((size_t)MAXROWS * 4);
  float* wt     = (float*)alloc((size_t)MAXROWS * 4);
  int*   es     = (int*)  alloc((size_t)2 * T_TOKENS * 4);
  float* wsv    = (float*)alloc((size_t)2 * T_TOKENS * 4);
  int*   counts = (int*)  alloc(64);
  int*   offs   = (int*)  alloc(64);
  int*   cursor = (int*)  alloc(64);

  hipMemsetAsync(counts, 0, 64, stream);
  hipMemsetAsync(perm, 0xFF, (size_t)MAXROWS * 4, stream);

  router_kernel<<<T_TOKENS / 4, 256, 0, stream>>>(x, gw, xb, es, wsv, counts);
  offsets_kernel<<<1, 64, 0, stream>>>(counts, offs, cursor);
  assign_kernel<<<T_TOKENS / 256, 256, 0, stream>>>(es, wsv, offs, cursor, perm, wt);

  // w1 [E][D][H] -> w1t [E][H][D]
  transpose_cvt_kernel<<<dim3(HDIM / 64, DMODEL / 64, NEXP), 256, 0, stream>>>(w1, w1t, DMODEL, HDIM);
  // w2 [E][H][D] -> w2t [E][D][H]
  transpose_cvt_kernel<<<dim3(DMODEL / 64, HDIM / 64, NEXP), 256, 0, stream>>>(w2, w2t, HDIM, DMODEL);

  out_init_kernel<<<(T_TOKENS * DMODEL) / 256, 256, 0, stream>>>(out, bias);

  // G1: [rows,1024] x w1t[e][2048,1024]^T -> gelu -> hidden ; BN=256 (FN=4)
  moe_gemm256_kernel<DMODEL, HDIM, 4, true><<<MTILES * 8, 512, 0, stream>>>(
      xb, w1t, hidden, nullptr, perm, wt, offs);
  // G2: hidden[rows,2048] x w2t[e][1024,2048]^T -> atomic scatter ; BN=128 (FN=2)
  moe_gemm256_kernel<HDIM, DMODEL, 2, false><<<MTILES * 8, 512, 0, stream>>>(
      hidden, w2t, nullptr, out, perm, wt, offs);
}

// Round 4
// 425.020 us; speedup vs baseline: 1.0256x; 1.0256x over previous
//
#include <hip/hip_runtime.h>
#include <hip/hip_bf16.h>
#include <cmath>

// ---------------- problem constants ----------------
#define T_TOKENS 4096   // 2*2048
#define DMODEL   1024
#define HDIM     2048
#define NEXP     8
#define BM 256          // M-tile (rows padded per expert to 256)
#define BK 64
#define MAXROWS 10240   // 8192 routed rows + worst-case per-expert padding to 256
#define MTILES  (MAXROWS / BM)   // 40

typedef __bf16 bf16;
typedef __bf16 bf16x8 __attribute__((ext_vector_type(8)));
typedef __bf16 bf16x4 __attribute__((ext_vector_type(4)));
typedef float  f32x4  __attribute__((ext_vector_type(4)));

__device__ inline void gload_lds16(const void* g, void* l) {
  __builtin_amdgcn_global_load_lds(
      (const __attribute__((address_space(1))) void*)g,
      (__attribute__((address_space(3))) void*)l, 16, 0, 0);
}

// ---------------- router ----------------
__global__ __launch_bounds__(256) void router_kernel(
    const float* __restrict__ x, const float* __restrict__ gw,
    bf16* __restrict__ xb, int* __restrict__ es, float* __restrict__ wsv,
    int* __restrict__ counts)
{
  int wid = threadIdx.x >> 6, lane = threadIdx.x & 63;
  int t = blockIdx.x * 4 + wid;
  if (t >= T_TOKENS) return;
  const float* xrow = x + (size_t)t * DMODEL;

  double acc[NEXP];
#pragma unroll
  for (int e = 0; e < NEXP; e++) acc[e] = 0.0;

#pragma unroll
  for (int i = 0; i < 4; i++) {
    int d0 = (i * 64 + lane) * 4;
    float4 xv = *(const float4*)(xrow + d0);
    bf16x4 o = { (bf16)xv.x, (bf16)xv.y, (bf16)xv.z, (bf16)xv.w };
    *(bf16x4*)(xb + (size_t)t * DMODEL + d0) = o;
    const float* g0 = gw + (size_t)d0 * NEXP;
    float xs[4] = { xv.x, xv.y, xv.z, xv.w };
#pragma unroll
    for (int j = 0; j < 4; j++)
#pragma unroll
      for (int e = 0; e < NEXP; e++)
        acc[e] += (double)xs[j] * (double)g0[j * NEXP + e];
  }
#pragma unroll
  for (int e = 0; e < NEXP; e++) {
    double v = acc[e];
#pragma unroll
    for (int m = 32; m >= 1; m >>= 1) v += __shfl_xor(v, m, 64);
    acc[e] = v;
  }
  if (lane == 0) {
    float l[NEXP], p[NEXP];
    float mx = -1e30f;
#pragma unroll
    for (int e = 0; e < NEXP; e++) { l[e] = (float)acc[e]; mx = fmaxf(mx, l[e]); }
    float s = 0.f;
#pragma unroll
    for (int e = 0; e < NEXP; e++) { p[e] = __expf(l[e] - mx); s += p[e]; }
#pragma unroll
    for (int e = 0; e < NEXP; e++) p[e] /= s;
    int i0 = 0;
#pragma unroll
    for (int e = 1; e < NEXP; e++) if (p[e] > p[i0]) i0 = e;
    int i1 = (i0 == 0) ? 1 : 0;
#pragma unroll
    for (int e = 0; e < NEXP; e++) if (e != i0 && p[e] > p[i1]) i1 = e;
    float wA = p[i0], wB = p[i1];
    float dn = wA + wB + 1e-9f;
    wA /= dn; wB /= dn;
    es[t] = i0; es[T_TOKENS + t] = i1;
    wsv[t] = wA; wsv[T_TOKENS + t] = wB;
    atomicAdd(&counts[i0], 1);
    atomicAdd(&counts[i1], 1);
  }
}

// ---------------- padded prefix offsets, zero cursors ----------------
__global__ void offsets_kernel(const int* __restrict__ counts, int* __restrict__ off,
                               int* __restrict__ cursor)
{
  if (threadIdx.x == 0) {
    int o = 0;
    for (int e = 0; e < NEXP; e++) {
      off[e] = o;
      o += ((counts[e] + BM - 1) / BM) * BM;
    }
    off[NEXP] = o;
  }
  if (threadIdx.x < NEXP) cursor[threadIdx.x] = 0;
}

// ---------------- token -> row assignment ----------------
__global__ void assign_kernel(const int* __restrict__ es, const float* __restrict__ wsv,
                              const int* __restrict__ off, int* __restrict__ cursor,
                              int* __restrict__ perm, float* __restrict__ wt)
{
  int t = blockIdx.x * blockDim.x + threadIdx.x;
  if (t >= T_TOKENS) return;
#pragma unroll
  for (int s = 0; s < 2; s++) {
    int e = es[s * T_TOKENS + t];
    int slot = atomicAdd(&cursor[e], 1);
    int r = off[e] + slot;
    perm[r] = t;
    wt[r] = wsv[s * T_TOKENS + t];
  }
}

// ---------------- weight fp32 [E][R][C] -> bf16 transposed [E][C][R] ----------------
__global__ __launch_bounds__(256) void transpose_cvt_kernel(
    const float* __restrict__ src, bf16* __restrict__ dst, int R, int C)
{
  __shared__ bf16 tile[64][66];
  int e = blockIdx.z;
  int r0 = blockIdx.y * 64, c0 = blockIdx.x * 64;
  const float* s = src + (size_t)e * R * C;
  bf16* d = dst + (size_t)e * R * C;
  int tr = threadIdx.x >> 4;
  int tc4 = (threadIdx.x & 15) * 4;
#pragma unroll
  for (int i = 0; i < 4; i++) {
    int r = tr + i * 16;
    float4 v = *(const float4*)(s + (size_t)(r0 + r) * C + c0 + tc4);
    tile[tc4 + 0][r] = (bf16)v.x;
    tile[tc4 + 1][r] = (bf16)v.y;
    tile[tc4 + 2][r] = (bf16)v.z;
    tile[tc4 + 3][r] = (bf16)v.w;
  }
  __syncthreads();
  int cc0 = threadIdx.x >> 3;
  int ch = (threadIdx.x & 7) * 8;
#pragma unroll
  for (int i = 0; i < 2; i++) {
    int cc = cc0 + i * 32;
    const unsigned int* rp = (const unsigned int*)&tile[cc][0];
    unsigned int u0 = rp[ch / 2 + 0];
    unsigned int u1 = rp[ch / 2 + 1];
    unsigned int u2 = rp[ch / 2 + 2];
    unsigned int u3 = rp[ch / 2 + 3];
    uint4 o = { u0, u1, u2, u3 };
    *(uint4*)(d + (size_t)(c0 + cc) * R + r0 + ch) = o;
  }
}

// ---------------- out = bias (broadcast) ----------------
__global__ void out_init_kernel(float* __restrict__ out, const float* __restrict__ bias)
{
  int i = blockIdx.x * blockDim.x + threadIdx.x;
  out[i] = bias[i & (DMODEL - 1)];
}

// ---------------- counted-vmcnt pipelined MFMA GEMM (T1+T2+T3+T4+T5) ----------------
// 512 thr = 8 waves (2M x 4N); per-wave out 128 x (FN*16). BN = FN*64.
// 4 phases/K-tile, each phase stages ONE quarter-group of tile t+1 and gates with
// counted vmcnt (6 for G1; 5/5/4 for G2) -- never drains to 0 in the loop.
// LDS rows are GROUP-MAJOR remapped so each 64-row load block = one phase's read set:
//   A: g = ((s>>6)&1)*128 + (s>>7)*64 + (s&63)      (regroup by qm)
//   B(FN=4): g = ((s>>5)&3)*64 + (s>>7)*32 + (s&31) (regroup by qn)
//   B(FN=2): g = ((s>>4)&3)*32 + (s>>6)*16 + (s&15)
// XOR swizzle byte^=(s&7)<<4 on read; source col pre-swizzled (rule #21).
template<int KDIM, int NDIM, int FN, bool GELU_STORE>
__global__ __launch_bounds__(512, 2) void moe_gemm256_kernel(
    const bf16* __restrict__ A, const bf16* __restrict__ W,
    bf16* __restrict__ hidden, float* __restrict__ out,
    const int* __restrict__ perm, const float* __restrict__ wt,
    const int* __restrict__ off)
{
  constexpr int BN_ = FN * 64;
  constexpr int NQ  = FN / 2;
  constexpr int NT  = KDIM / BK;
  constexpr int BLOADS = FN;

  int nt = blockIdx.x & 7;
  int mt = blockIdx.x >> 3;
  int row0 = mt * BM;
  int total = off[NEXP];
  if (row0 >= total) return;
  int e = 0;
  while (row0 >= off[e + 1]) e++;
  int n0 = nt * BN_;
  const bf16* Wb = W + (size_t)e * NDIM * KDIM;

  __shared__ bf16 As[2][256 * 64];
  __shared__ bf16 Bs[2][BN_ * 64];

  int tid  = threadIdx.x;
  int lane = tid & 63;
  int wid  = tid >> 6;
  int wm   = wid >> 2;
  int wn   = wid & 3;
  int l15  = lane & 15;
  int hi16 = (lane >> 4) << 4;
  int srow = tid >> 3;                          // 0..63
  int scol = ((tid & 7) ^ (srow & 7)) * 8;      // pre-swizzled source col (elems)

  unsigned aoff[4];
#pragma unroll
  for (int i = 0; i < 4; ++i) {
    int s = i * 64 + srow;
    int g = ((s >> 6) & 1) * 128 + (s >> 7) * 64 + (s & 63);
    unsigned rowid;
    if (GELU_STORE) { int p = perm[row0 + g]; rowid = (p < 0) ? 0u : (unsigned)p; }
    else            { rowid = (unsigned)(row0 + g); }
    aoff[i] = rowid * (unsigned)KDIM;
  }
  unsigned boff[BLOADS];
#pragma unroll
  for (int i = 0; i < BLOADS; ++i) {
    int s = i * 64 + srow;
    int g;
    if constexpr (FN == 4) g = ((s >> 5) & 3) * 64 + (s >> 7) * 32 + (s & 31);
    else                   g = ((s >> 4) & 3) * 32 + (s >> 6) * 16 + (s & 15);
    boff[i] = (unsigned)(n0 + g) * (unsigned)KDIM;
  }

  f32x4 acc[8][FN];
#pragma unroll
  for (int am = 0; am < 8; ++am)
#pragma unroll
    for (int an = 0; an < FN; ++an)
      acc[am][an] = (f32x4){0.f, 0.f, 0.f, 0.f};

#define STAGE_A(bb, t, grp) do {                                             \
    int k0_ = (t) * BK;                                                      \
    _Pragma("unroll")                                                        \
    for (int i = 2 * (grp); i < 2 * (grp) + 2; ++i)                          \
      gload_lds16(A + aoff[i] + k0_ + scol, &As[bb][(unsigned)(i * 512 + tid) * 8]); \
  } while (0)

#define STAGE_B(bb, t, grp) do {                                             \
    int k0_ = (t) * BK;                                                      \
    _Pragma("unroll")                                                        \
    for (int i = (BLOADS / 2) * (grp); i < (BLOADS / 2) * ((grp) + 1); ++i)  \
      gload_lds16(Wb + boff[i] + k0_ + scol, &Bs[bb][(unsigned)(i * 512 + tid) * 8]); \
  } while (0)

  bf16x8 af[4][2];
  bf16x8 bfr[2][NQ][2];

#define READ_A(bb, qm) do {                                                  \
    const char* base_ = (const char*)&As[bb][0];                             \
    _Pragma("unroll")                                                        \
    for (int m = 0; m < 4; ++m)                                              \
      _Pragma("unroll")                                                      \
      for (int kk = 0; kk < 2; ++kk) {                                       \
        int s_  = (qm) * 128 + wm * 64 + m * 16 + l15;                       \
        int cb_ = (kk * 64 + hi16) ^ ((s_ & 7) << 4);                        \
        af[m][kk] = *(const bf16x8*)(base_ + s_ * 128 + cb_);                \
      }                                                                      \
  } while (0)

#define READ_B(bb, qn) do {                                                  \
    const char* base_ = (const char*)&Bs[bb][0];                             \
    _Pragma("unroll")                                                        \
    for (int n = 0; n < NQ; ++n)                                             \
      _Pragma("unroll")                                                      \
      for (int kk = 0; kk < 2; ++kk) {                                       \
        int s_  = (qn) * (BN_ / 2) + wn * (BN_ / 8) + n * 16 + l15;          \
        int cb_ = (kk * 64 + hi16) ^ ((s_ & 7) << 4);                        \
        bfr[qn][n][kk] = *(const bf16x8*)(base_ + s_ * 128 + cb_);           \
      }                                                                      \
  } while (0)

#define DO_MFMA(qm, qn) do {                                                 \
    __builtin_amdgcn_s_setprio(1);                                           \
    _Pragma("unroll")                                                        \
    for (int m = 0; m < 4; ++m)                                              \
      _Pragma("unroll")                                                      \
      for (int n = 0; n < NQ; ++n)                                           \
        _Pragma("unroll")                                                    \
        for (int kk = 0; kk < 2; ++kk)                                       \
          acc[(qm) * 4 + m][(qn) * NQ + n] = __builtin_amdgcn_mfma_f32_16x16x32_bf16( \
              af[m][kk], bfr[qn][n][kk], acc[(qm) * 4 + m][(qn) * NQ + n], 0, 0, 0); \
    __builtin_amdgcn_s_setprio(0);                                           \
    __builtin_amdgcn_sched_barrier(0);                                       \
  } while (0)

#define GATE_A  do { if constexpr (FN == 4) asm volatile("s_waitcnt vmcnt(6)" ::: "memory"); \
                     else                   asm volatile("s_waitcnt vmcnt(5)" ::: "memory"); } while (0)
#define GATE_C  do { if constexpr (FN == 4) asm volatile("s_waitcnt vmcnt(6)" ::: "memory"); \
                     else                   asm volatile("s_waitcnt vmcnt(4)" ::: "memory"); } while (0)
#define LGKM_SB do { asm volatile("s_waitcnt lgkmcnt(0)" ::: "memory");      \
                     __builtin_amdgcn_sched_barrier(0); } while (0)

  // prologue: full tile 0, drain once
  STAGE_A(0, 0, 0); STAGE_B(0, 0, 0); STAGE_B(0, 0, 1); STAGE_A(0, 0, 1);
  asm volatile("s_waitcnt vmcnt(0)" ::: "memory");
  __builtin_amdgcn_s_barrier();

  for (int t = 0; t < NT; ++t) {
    int b = t & 1;
    bool pf = (t + 1 < NT);
    // ---- phase 0: (qm0,qn0); stage A-g0(t+1)
    if (pf) STAGE_A(b ^ 1, t + 1, 0);
    GATE_A;
    __builtin_amdgcn_s_barrier();
    READ_A(b, 0); READ_B(b, 0);
    LGKM_SB;
    DO_MFMA(0, 0);
    // ---- phase 1: (qm0,qn1); stage B-g0(t+1)
    if (pf) STAGE_B(b ^ 1, t + 1, 0);
    GATE_A;
    __builtin_amdgcn_s_barrier();
    READ_B(b, 1);
    LGKM_SB;
    DO_MFMA(0, 1);
    // ---- phase 2: (qm1,qn0); stage B-g1(t+1)
    if (pf) STAGE_B(b ^ 1, t + 1, 1);
    GATE_C;
    __builtin_amdgcn_s_barrier();
    READ_A(b, 1);
    LGKM_SB;
    DO_MFMA(1, 0);
    // ---- phase 3: (qm1,qn1); stage A-g1(t+1); no gate needed
    if (pf) STAGE_A(b ^ 1, t + 1, 1);
    __builtin_amdgcn_s_barrier();
    DO_MFMA(1, 1);
  }

#undef STAGE_A
#undef STAGE_B
#undef READ_A
#undef READ_B
#undef DO_MFMA
#undef GATE_A
#undef GATE_C
#undef LGKM_SB

  // epilogue: C/D layout col = lane&15, row = (lane>>4)*4 + j
#pragma unroll
  for (int am = 0; am < 8; ++am) {
    int rb = row0 + wm * 128 + am * 16 + ((lane >> 4) << 2);
#pragma unroll
    for (int j = 0; j < 4; ++j) {
      int rg = rb + j;
      if (GELU_STORE) {
#pragma unroll
        for (int an = 0; an < FN; ++an) {
          float v  = acc[am][an][j];
          float gv = 0.5f * v * (1.0f + erff(v * 0.70710678118654752f));
          hidden[(unsigned)rg * NDIM + (n0 + wn * (FN * 16) + an * 16 + l15)] = (bf16)gv;
        }
      } else {
        int p = perm[rg];
        if (p >= 0) {
          float w = wt[rg];
#pragma unroll
          for (int an = 0; an < FN; ++an)
            atomicAdd(&out[(unsigned)p * DMODEL + (n0 + wn * (FN * 16) + an * 16 + l15)],
                      w * acc[am][an][j]);
        }
      }
    }
  }
}

// ---------------- host ----------------
extern "C" void kernel_launch(void* const* d_in, const int* in_sizes, int n_in,
                              void* d_out, int out_size, void* d_ws, size_t ws_size,
                              hipStream_t stream)
{
  const float* x    = (const float*)d_in[0];
  const float* gw   = (const float*)d_in[1];
  const float* w1   = (const float*)d_in[2];
  const float* w2   = (const float*)d_in[3];
  const float* bias = (const float*)d_in[4];
  float* out = (float*)d_out;

  char* ws = (char*)d_ws;
  size_t o = 0;
  auto alloc = [&](size_t bytes) {
    void* p = ws + o;
    o = (o + bytes + 255) & ~(size_t)255;
    return p;
  };
  bf16*  xb     = (bf16*) alloc((size_t)T_TOKENS * DMODEL * 2);
  bf16*  w1t    = (bf16*) alloc((size_t)NEXP * HDIM * DMODEL * 2);   // [E][H][D]
  bf16*  w2t    = (bf16*) alloc((size_t)NEXP * DMODEL * HDIM * 2);   // [E][D][H]
  bf16*  hidden = (bf16*) alloc((size_t)MAXROWS * HDIM * 2);
  int*   perm   = (int*)  alloc((size_t)MAXROWS * 4);
  float* wt     = (float*)alloc((size_t)MAXROWS * 4);
  int*   es     = (int*)  alloc((size_t)2 * T_TOKENS * 4);
  float* wsv    = (float*)alloc((size_t)2 * T_TOKENS * 4);
  int*   counts = (int*)  alloc(64);
  int*   offs   = (int*)  alloc(64);
  int*   cursor = (int*)  alloc(64);

  hipMemsetAsync(counts, 0, 64, stream);
  hipMemsetAsync(perm, 0xFF, (size_t)MAXROWS * 4, stream);

  router_kernel<<<T_TOKENS / 4, 256, 0, stream>>>(x, gw, xb, es, wsv, counts);
  offsets_kernel<<<1, 64, 0, stream>>>(counts, offs, cursor);
  assign_kernel<<<T_TOKENS / 256, 256, 0, stream>>>(es, wsv, offs, cursor, perm, wt);

  // w1 [E][D][H] -> w1t [E][H][D]
  transpose_cvt_kernel<<<dim3(HDIM / 64, DMODEL / 64, NEXP), 256, 0, stream>>>(w1, w1t, DMODEL, HDIM);
  // w2 [E][H][D] -> w2t [E][D][H]
  transpose_cvt_kernel<<<dim3(DMODEL / 64, HDIM / 64, NEXP), 256, 0, stream>>>(w2, w2t, HDIM, DMODEL);

  out_init_kernel<<<(T_TOKENS * DMODEL) / 256, 256, 0, stream>>>(out, bias);

  // G1: [rows,1024] x w1t[e][2048,1024]^T -> gelu -> hidden ; BN=256 (FN=4)
  moe_gemm256_kernel<DMODEL, HDIM, 4, true><<<MTILES * 8, 512, 0, stream>>>(
      xb, w1t, hidden, nullptr, perm, wt, offs);
  // G2: hidden[rows,2048] x w2t[e][1024,2048]^T -> atomic scatter ; BN=128 (FN=2)
  moe_gemm256_kernel<HDIM, DMODEL, 2, false><<<MTILES * 8, 512, 0, stream>>>(
      hidden, w2t, nullptr, out, perm, wt, offs);
}